// Round 11
// baseline (4589.825 us; speedup 1.0000x reference)
//
#include <hip/hip_runtime.h>

typedef unsigned short u16;
typedef unsigned int u32;
typedef unsigned long long u64;
typedef float f32x4 __attribute__((ext_vector_type(4)));
typedef u32 u32x4 __attribute__((ext_vector_type(4)));
typedef __bf16 bf16x8 __attribute__((ext_vector_type(8)));

#define KPAD 416   // 400 padded to 13*32
#define SWZ(r) ((((u32)(r)) & 3u) ^ ((((u32)(r)) >> 2) & 3u))

__device__ __forceinline__ float bf2f(u16 v){
  u32 x = ((u32)v) << 16; float f; __builtin_memcpy(&f, &x, 4); return f;
}
__device__ __forceinline__ u16 f2bf(float f){
  u32 x; __builtin_memcpy(&x, &f, 4);
  x += 0x7fffu + ((x >> 16) & 1u);
  return (u16)(x >> 16);
}
__device__ __forceinline__ void gll16(const u16* g, void* l){
  __builtin_amdgcn_global_load_lds(
      (const __attribute__((address_space(1))) u32*)(const void*)g,
      (__attribute__((address_space(3))) u32*)l, 16, 0, 0);
}
__device__ __forceinline__ int xcd_remap(int orig, int nwg){
  int q = nwg >> 3, r = nwg & 7;
  int xcd = orig & 7, idx = orig >> 3;
  return (xcd < r ? xcd * (q + 1) : r * (q + 1) + (xcd - r) * q) + idx;
}

// ---------------- embedding: cast table to bf16, then gather as u64 -------------
__global__ void cast_emb(const float* __restrict__ src, u16* __restrict__ dst, int n){
  int t = blockIdx.x * 256 + threadIdx.x;
  if (t < n) dst[t] = f2bf(src[t]);
}
__global__ void embed_k(const int* __restrict__ x, const u16* __restrict__ embB,
                        u16* __restrict__ H, int N){
  int tid = blockIdx.x * 256 + threadIdx.x;
  if (tid >= N * 104) return;
  int n = tid / 104, cg = tid % 104, c = cg * 4;
  u64 pack = 0;
  if (c < 400){
    int t = c / 20, d = c % 20;
    int tok = x[n * 20 + t];
    pack = *(const u64*)(embB + (size_t)tok * 20 + d);   // 4 bf16, 8B-aligned
  }
  *(u64*)(H + (size_t)n * KPAD + c) = pack;
}

// ---------------- weight transpose+pad+bf16: dst[n][k] = src[k][n] -------------
__global__ void convw_k(const float* __restrict__ src, u16* __restrict__ dst,
                        int srccols, int nout){
  int tid = blockIdx.x * 256 + threadIdx.x;
  if (tid >= nout * KPAD) return;
  int k = tid % KPAD, n = tid / KPAD;
  dst[tid] = (k < 400) ? f2bf(src[(size_t)k * srccols + n]) : (u16)0;
}

// ---------------- pad+cast w: wPad[l][k][c] = bf16(w[l][k][c]), c-pad to 416 ----
__global__ void pad_w(const float* __restrict__ src, u16* __restrict__ dst, int rows){
  int tid = blockIdx.x * 256 + threadIdx.x;
  if (tid >= rows * KPAD) return;
  int k = tid / KPAD, c = tid % KPAD;
  dst[tid] = (c < 400) ? f2bf(src[(size_t)k * 400 + c]) : (u16)0;
}

// ---------------- CSR build ----------------------------------------------------
__global__ void count_k(const int* __restrict__ ei, int* __restrict__ cnt, int E){
  int t = blockIdx.x * 256 + threadIdx.x; if (t >= E) return;
  atomicAdd(&cnt[ei[E + t] + 1], 1);
}
__global__ void scan_blk(int* __restrict__ data, int* __restrict__ bsum, int total){
  __shared__ int sm[1024];
  int gid = blockIdx.x * 1024 + threadIdx.x;
  sm[threadIdx.x] = (gid < total) ? data[gid] : 0;
  __syncthreads();
  for (int off = 1; off < 1024; off <<= 1){
    int add = (threadIdx.x >= off) ? sm[threadIdx.x - off] : 0;
    __syncthreads();
    sm[threadIdx.x] += add;
    __syncthreads();
  }
  if (gid < total) data[gid] = sm[threadIdx.x];
  if (threadIdx.x == 1023 && bsum) bsum[blockIdx.x] = sm[1023];
}
// adds block prefix AND writes cur[] copy (folds old copy_k)
__global__ void scan_add(int* __restrict__ data, const int* __restrict__ bsum,
                         int* __restrict__ cur, int total, int N){
  int gid = blockIdx.x * 256 + threadIdx.x;
  if (gid >= total) return;
  int b = gid >> 10;
  int v = data[gid];
  if (b > 0){ v += bsum[b - 1]; data[gid] = v; }
  if (gid < N) cur[gid] = v;
}
__global__ void fill_k(const int* __restrict__ ei, int* __restrict__ cur,
                       int* __restrict__ srcl, int E){
  int t = blockIdx.x * 256 + threadIdx.x; if (t >= E) return;
  int d = ei[E + t];
  int p = atomicAdd(&cur[d], 1);
  srcl[p] = ei[t];
}
__global__ void bound_k(const int* __restrict__ bseg, int* __restrict__ segs, int N){
  int t = threadIdx.x; if (t > 128) return;
  int lo = 0, hi = N;
  while (lo < hi){ int mid = (lo + hi) >> 1; if (bseg[mid] < t) lo = mid + 1; else hi = mid; }
  segs[t] = lo;
}

// ---------------- hagg[n] = sum over in-edges of h[src]; wave per node ----------
// 2-edge unroll with independent row gathers to double memory-level parallelism.
__global__ void seg_sum(const int* __restrict__ offs, const int* __restrict__ srcl,
                        const u32* __restrict__ Mv, u32* __restrict__ Agg, int N){
  int n = blockIdx.x * 4 + (threadIdx.x >> 6);
  int lane = threadIdx.x & 63;
  if (n >= N || lane >= 52) return;
  int s = offs[n], e = offs[n + 1];
  const u32* Mvl = Mv + lane * 4;
  float a[8] = {0.f,0.f,0.f,0.f,0.f,0.f,0.f,0.f};
  float b[8] = {0.f,0.f,0.f,0.f,0.f,0.f,0.f,0.f};
  int i = s;
  for (; i + 1 < e; i += 2){
    int sr0 = srcl[i], sr1 = srcl[i + 1];
    u32x4 v = *(const u32x4*)(Mvl + (size_t)sr0 * 208);
    u32x4 w = *(const u32x4*)(Mvl + (size_t)sr1 * 208);
    a[0] += bf2f((u16)(v[0] & 0xffffu)); a[1] += bf2f((u16)(v[0] >> 16));
    a[2] += bf2f((u16)(v[1] & 0xffffu)); a[3] += bf2f((u16)(v[1] >> 16));
    a[4] += bf2f((u16)(v[2] & 0xffffu)); a[5] += bf2f((u16)(v[2] >> 16));
    a[6] += bf2f((u16)(v[3] & 0xffffu)); a[7] += bf2f((u16)(v[3] >> 16));
    b[0] += bf2f((u16)(w[0] & 0xffffu)); b[1] += bf2f((u16)(w[0] >> 16));
    b[2] += bf2f((u16)(w[1] & 0xffffu)); b[3] += bf2f((u16)(w[1] >> 16));
    b[4] += bf2f((u16)(w[2] & 0xffffu)); b[5] += bf2f((u16)(w[2] >> 16));
    b[6] += bf2f((u16)(w[3] & 0xffffu)); b[7] += bf2f((u16)(w[3] >> 16));
  }
  if (i < e){
    u32x4 v = *(const u32x4*)(Mvl + (size_t)srcl[i] * 208);
    a[0] += bf2f((u16)(v[0] & 0xffffu)); a[1] += bf2f((u16)(v[0] >> 16));
    a[2] += bf2f((u16)(v[1] & 0xffffu)); a[3] += bf2f((u16)(v[1] >> 16));
    a[4] += bf2f((u16)(v[2] & 0xffffu)); a[5] += bf2f((u16)(v[2] >> 16));
    a[6] += bf2f((u16)(v[3] & 0xffffu)); a[7] += bf2f((u16)(v[3] >> 16));
  }
#pragma unroll
  for (int j = 0; j < 8; j++) a[j] += b[j];
  u32* q = Agg + (size_t)n * 208 + lane * 4;
  q[0] = (u32)f2bf(a[0]) | ((u32)f2bf(a[1]) << 16);
  q[1] = (u32)f2bf(a[2]) | ((u32)f2bf(a[3]) << 16);
  q[2] = (u32)f2bf(a[4]) | ((u32)f2bf(a[5]) << 16);
  q[3] = (u32)f2bf(a[6]) | ((u32)f2bf(a[7]) << 16);
}

// ---------------- GEMM: C[M][416] = A[M][416] @ BT[ncols][416]^T ----------------
// 128x64 tile, 2-phase dbuf; per-layer weight fold (M=1200). Batched over nfold
// (BT, C) pairs; A advances every 3 folds (degenerates to A0 for nfold<=3).
__launch_bounds__(256, 2)
__global__ void gemm_msg(const u16* __restrict__ A0, const u16* __restrict__ BT0,
                         u16* __restrict__ C0, int M, int nwg, int nfold){
  __shared__ __align__(16) u16 smem[2][192 * 32];   // per buf: lA 8192B + lB 4096B
  const int tid = threadIdx.x, lane = tid & 63, wave = tid >> 6;
  const int wgall = xcd_remap(blockIdx.x, nwg * nfold);
  const int fold = wgall / nwg, wg = wgall % nwg;
  const u16* A = A0 + (size_t)(fold / 3) * 1200 * KPAD;
  const u16* BT = BT0 + (size_t)fold * 400 * KPAD;
  u16* C = C0 + (size_t)fold * 1200 * KPAD;
  const int m0 = (wg / 7) * 128, n0 = (wg % 7) * 64;

  const u16* gsrc[3]; u32 ldo[3];
#pragma unroll
  for (int i = 0; i < 2; i++){
    u32 o = (u32)(wave * 2 + i) * 1024 + (u32)lane * 16;
    u32 r = o >> 6, cch = (o >> 4) & 3;
    int grow = m0 + (int)r; if (grow > M - 1) grow = M - 1;
    gsrc[i] = A + (size_t)grow * KPAD + ((cch ^ SWZ(r)) << 3);
    ldo[i] = o;
  }
  {
    u32 o = (u32)wave * 1024 + (u32)lane * 16;
    u32 r = o >> 6, cch = (o >> 4) & 3;
    int gn = n0 + (int)r; if (gn > 399) gn = 399;
    gsrc[2] = BT + (size_t)gn * KPAD + ((cch ^ SWZ(r)) << 3);
    ldo[2] = 8192 + o;
  }
  auto stage = [&](int p, int ks){
#pragma unroll
    for (int i = 0; i < 3; i++)
      gll16(gsrc[i] + ks * 32, (char*)smem + (size_t)p * 12288 + ldo[i]);
  };

  const int g = lane >> 4, rl = lane & 15;
  const int ar0 = wave * 32 + rl, ar1 = ar0 + 16;
  const u32 aoff0 = (u32)ar0 * 64 + ((g ^ SWZ(ar0)) << 4);
  const u32 aoff1 = (u32)ar1 * 64 + ((g ^ SWZ(ar1)) << 4);
  u32 boff[4];
#pragma unroll
  for (int j = 0; j < 4; j++){
    int br = j * 16 + rl;
    boff[j] = 8192u + (u32)br * 64 + ((g ^ SWZ(br)) << 4);
  }

  f32x4 zero = {0.f, 0.f, 0.f, 0.f};
  f32x4 acc[2][4];
#pragma unroll
  for (int i = 0; i < 2; i++)
#pragma unroll
    for (int j = 0; j < 4; j++) acc[i][j] = zero;

  stage(0, 0);
  __syncthreads();
  int cur = 0;
  for (int ks = 0; ks < 13; ks++){
    if (ks < 12) stage(cur ^ 1, ks + 1);
    const char* sb = (const char*)smem + (size_t)cur * 12288;
    bf16x8 a0 = *(const bf16x8*)(sb + aoff0);
    bf16x8 a1 = *(const bf16x8*)(sb + aoff1);
#pragma unroll
    for (int j = 0; j < 4; j++){
      bf16x8 bb = *(const bf16x8*)(sb + boff[j]);
      acc[0][j] = __builtin_amdgcn_mfma_f32_16x16x32_bf16(a0, bb, acc[0][j], 0, 0, 0);
      acc[1][j] = __builtin_amdgcn_mfma_f32_16x16x32_bf16(a1, bb, acc[1][j], 0, 0, 0);
    }
    __syncthreads();
    cur ^= 1;
  }

  const int rsub = (lane >> 4) * 4;
#pragma unroll
  for (int i = 0; i < 2; i++){
#pragma unroll
    for (int j = 0; j < 4; j++){
      int col = n0 + j * 16 + rl;
      if (col >= KPAD) continue;
#pragma unroll
      for (int r = 0; r < 4; r++){
        int row = m0 + wave * 32 + i * 16 + rsub + r;
        if (row >= M) continue;
        C[(size_t)row * KPAD + col] = (col < 400) ? f2bf(acc[i][j][r]) : (u16)0;
      }
    }
  }
}

// ---------------- fused GRU GEMM, 128x16 tile for occupancy ---------------------
// Same pipeline skeleton as the proven R1 structure (A direct global->reg, B
// triple-buffered via gll16, counted vmcnt, raw barrier), but the col-window is
// halved to 16 so the accumulator is 48 VGPRs (6 gates x 2 rowfrags x f32x4).
// Target: <=128 VGPR -> 4 blocks / 16 waves per CU (was ~180 VGPR / 10 waves).
// Staging: 6 x 1KB gate tiles split 2/2/1/1 across waves; per-wave counted
// vmcnt = nt+4 (6 heavy / 5 light); final step vmcnt(4).
__launch_bounds__(256, 4)
__global__ void gemm_gru(const u16* __restrict__ AG, const u16* __restrict__ AH,
                         const u16* __restrict__ WCT, const u16* __restrict__ WHHT,
                         const float* __restrict__ bih, const float* __restrict__ bhh,
                         u16* __restrict__ Out, int M, int nwg){
  __shared__ __align__(16) u16 lB[3][3072];    // 3 bufs x 6KB: 6 tiles x 16col x 64B
  const int tid = threadIdx.x, lane = tid & 63, wave = tid >> 6;
  const int wg = xcd_remap(blockIdx.x, nwg);
  const int m0 = (wg / 26) * 128, c0 = (wg % 26) * 16;

  // staging: waves 0,1 stage tiles {0,1},{2,3}; waves 2,3 stage {4},{5}
  const int nt = (wave < 2) ? 2 : 1;
  const int t0 = (wave < 2) ? wave * 2 : wave + 2;
  const u16* gsrcB[2]; u32 ldoB[2];
#pragma unroll
  for (int ii = 0; ii < 2; ii++){
    int tile = t0 + ii; if (tile > 5) tile = 5;
    const u16* Wsrc = (tile < 3) ? WCT : WHHT;
    int s = (tile < 3) ? tile : tile - 3;
    int r = lane >> 2, cch = lane & 3;
    int ncol = c0 + r; if (ncol > 399) ncol = 399;
    gsrcB[ii] = Wsrc + (size_t)(s * 400 + ncol) * KPAD + ((cch ^ SWZ(r)) << 3);
    ldoB[ii] = (u32)tile * 1024 + (u32)lane * 16;
  }
  auto stageB = [&](int p, int ks){
    gll16(gsrcB[0] + ks * 32, (char*)(&lB[0][0]) + (size_t)p * 6144 + ldoB[0]);
    if (nt == 2)
      gll16(gsrcB[1] + ks * 32, (char*)(&lB[0][0]) + (size_t)p * 6144 + ldoB[1]);
  };

  const int g = lane >> 4, rl = lane & 15;
  int rr0 = m0 + wave * 32 + rl;      if (rr0 > M - 1) rr0 = M - 1;
  int rr1 = m0 + wave * 32 + 16 + rl; if (rr1 > M - 1) rr1 = M - 1;
  const u16* pAG0 = AG + (size_t)rr0 * KPAD + g * 8;
  const u16* pAG1 = AG + (size_t)rr1 * KPAD + g * 8;
  const u16* pAH0 = AH + (size_t)rr0 * KPAD + g * 8;
  const u16* pAH1 = AH + (size_t)rr1 * KPAD + g * 8;

  const u32 boff = (u32)rl * 64 + ((g ^ SWZ(rl)) << 4);

  f32x4 zero = {0.f, 0.f, 0.f, 0.f};
  f32x4 acc[6][2];
#pragma unroll
  for (int t = 0; t < 6; t++)
#pragma unroll
    for (int i = 0; i < 2; i++) acc[t][i] = zero;

  bf16x8 aX[4], aY[4];
  auto loadA = [&](bf16x8 (&d)[4], int ks){
    d[0] = *(const bf16x8*)(pAG0 + ks * 32);
    d[1] = *(const bf16x8*)(pAG1 + ks * 32);
    d[2] = *(const bf16x8*)(pAH0 + ks * 32);
    d[3] = *(const bf16x8*)(pAH1 + ks * 32);
  };

  const int wcS = nt + 4;   // steady-state counted vmcnt (6 heavy / 5 light)
  auto body = [&](bf16x8 (&ac)[4], bf16x8 (&an)[4], int k, int wc){
    if (wc == 6)      asm volatile("s_waitcnt vmcnt(6)" ::: "memory");
    else if (wc == 5) asm volatile("s_waitcnt vmcnt(5)" ::: "memory");
    else              asm volatile("s_waitcnt vmcnt(4)" ::: "memory");
    __builtin_amdgcn_s_barrier();
    __builtin_amdgcn_sched_barrier(0);
    if (k + 2 <= 12) stageB((k + 2) % 3, k + 2);   // nt gll16
    if (k + 1 <= 12) loadA(an, k + 1);             // 4 reg loads
    const char* sb = (const char*)(&lB[0][0]) + (size_t)(k % 3) * 6144;
    __builtin_amdgcn_s_setprio(1);
#pragma unroll
    for (int t = 0; t < 6; t++){
      bf16x8 b = *(const bf16x8*)(sb + t * 1024 + boff);
      bf16x8 x0 = (t < 3) ? ac[0] : ac[2];
      bf16x8 x1 = (t < 3) ? ac[1] : ac[3];
      acc[t][0] = __builtin_amdgcn_mfma_f32_16x16x32_bf16(x0, b, acc[t][0], 0, 0, 0);
      acc[t][1] = __builtin_amdgcn_mfma_f32_16x16x32_bf16(x1, b, acc[t][1], 0, 0, 0);
    }
    __builtin_amdgcn_s_setprio(0);
  };

  // prologue: pin stage(buf0) as the oldest VMEM batch, then warm the pipe.
  stageB(0, 0);
  asm volatile("" ::: "memory");
  loadA(aX, 0);
  stageB(1, 1);

  body(aX, aY, 0, wcS);  body(aY, aX, 1, wcS);  body(aX, aY, 2, wcS);
  body(aY, aX, 3, wcS);  body(aX, aY, 4, wcS);  body(aY, aX, 5, wcS);
  body(aX, aY, 6, wcS);  body(aY, aX, 7, wcS);  body(aX, aY, 8, wcS);
  body(aY, aX, 9, wcS);  body(aX, aY, 10, wcS); body(aY, aX, 11, wcS);
  body(aX, aY, 12, 4);

  // ---- GRU epilogue: one col per lane group, 8 rows per lane ------------------
  const int rsub = g * 4;
  const int col = c0 + rl;
  const bool valid = col < 400;
  float bir = 0, biz = 0, bin = 0, bhr = 0, bhz = 0, bhn = 0;
  if (valid){
    bir = bih[col]; biz = bih[400 + col]; bin = bih[800 + col];
    bhr = bhh[col]; bhz = bhh[400 + col]; bhn = bhh[800 + col];
  }
#pragma unroll
  for (int i = 0; i < 2; i++){
#pragma unroll
    for (int r = 0; r < 4; r++){
      int row = m0 + wave * 32 + i * 16 + rsub + r;
      if (row >= M) continue;
      u16 outv = 0;
      if (valid){
        float ir = acc[0][i][r] + bir, iz = acc[1][i][r] + biz, inn = acc[2][i][r] + bin;
        float hr = acc[3][i][r] + bhr, hz = acc[4][i][r] + bhz, hn = acc[5][i][r] + bhn;
        float rg = 1.f / (1.f + __expf(-(ir + hr)));
        float zg = 1.f / (1.f + __expf(-(iz + hz)));
        float nx = inn + rg * hn;
        float tn = 1.f - 2.f / (1.f + __expf(2.f * nx));
        float hp = bf2f(AH[(size_t)row * KPAD + col]);
        float hv = (1.f - zg) * tn + zg * hp;
        outv = f2bf(hv);
      }
      Out[(size_t)row * KPAD + col] = outv;
    }
  }
}

// ---------------- pooled = segment_max(relu(h)); atomicMax on fp32 bits ---------
__global__ void pool_max(const u16* __restrict__ H, const int* __restrict__ segs,
                         u32* __restrict__ pooled, int goff){
  int b = blockIdx.x;
  int c = blockIdx.y * 256 + threadIdx.x;
  if (c >= 400) return;
  int s = segs[b], e = segs[b + 1], len = e - s;
  int chunk = blockIdx.z;
  int cs = s + (int)((long long)len * chunk / 4);
  int ce = s + (int)((long long)len * (chunk + 1) / 4);
  float mx = 0.f;
  for (int n = cs; n < ce; n++) mx = fmaxf(mx, bf2f(H[(size_t)n * KPAD + c]));
  if (mx > 0.f){
    u32 bits; __builtin_memcpy(&bits, &mx, 4);
    atomicMax(&pooled[b * 1200 + goff + c], bits);
  }
}

// ---------------- MLP: transpose W then wave-per-(4 rows x 1 col) dot -----------
__global__ void wt_k(const float* __restrict__ src, float* __restrict__ dst,
                     int K, int Nout){
  int t = blockIdx.x * 256 + threadIdx.x;
  if (t >= K * Nout) return;
  int n = t / K, k = t % K;
  dst[t] = src[(size_t)k * Nout + n];
}
__global__ void mlp_dot(const float* __restrict__ A, const float* __restrict__ WT,
                        const float* __restrict__ bias, float* __restrict__ out,
                        int K, int Nout){
  int gw = (int)((blockIdx.x * 256u + threadIdx.x) >> 6);
  int lane = threadIdx.x & 63;
  if (gw >= 32 * Nout) return;
  int mq = gw / Nout, n = gw % Nout;
  const float* w  = WT + (size_t)n * K;
  const float* a0 = A + (size_t)(mq * 4 + 0) * K;
  const float* a1 = A + (size_t)(mq * 4 + 1) * K;
  const float* a2 = A + (size_t)(mq * 4 + 2) * K;
  const float* a3 = A + (size_t)(mq * 4 + 3) * K;
  float c0 = 0.f, c1 = 0.f, c2 = 0.f, c3 = 0.f;
  for (int k = lane; k < K; k += 64){
    float wv = w[k];
    c0 = fmaf(a0[k], wv, c0);
    c1 = fmaf(a1[k], wv, c1);
    c2 = fmaf(a2[k], wv, c2);
    c3 = fmaf(a3[k], wv, c3);
  }
#pragma unroll
  for (int off = 32; off; off >>= 1){
    c0 += __shfl_xor(c0, off);
    c1 += __shfl_xor(c1, off);
    c2 += __shfl_xor(c2, off);
    c3 += __shfl_xor(c3, off);
  }
  if (lane == 0){
    float bn = bias[n];
    out[(size_t)(mq * 4 + 0) * Nout + n] = fmaxf(c0 + bn, 0.f);
    out[(size_t)(mq * 4 + 1) * Nout + n] = fmaxf(c1 + bn, 0.f);
    out[(size_t)(mq * 4 + 2) * Nout + n] = fmaxf(c2 + bn, 0.f);
    out[(size_t)(mq * 4 + 3) * Nout + n] = fmaxf(c3 + bn, 0.f);
  }
}

// ------------------------------------------------------------------------------
extern "C" void kernel_launch(void* const* d_in, const int* in_sizes, int n_in,
                              void* d_out, int out_size, void* d_ws, size_t ws_size,
                              hipStream_t stream){
  const int N = in_sizes[2];          // 100000
  const int E = in_sizes[1] / 2;      // 400000
  const int embN = in_sizes[3];       // V*D elements (f32)

  char* base = (char*)d_ws;
  size_t off = 0;
  auto alloc = [&](size_t sz) -> char* {
    char* r = base + off;
    off += (sz + 255) & ~(size_t)255;
    return r;
  };
  u16* hA    = (u16*)alloc((size_t)N * KPAD * 2);
  u16* hB    = (u16*)alloc((size_t)N * KPAD * 2);
  u16* hC    = (u16*)alloc((size_t)N * KPAD * 2);
  u16* wcT   = (u16*)alloc((size_t)3 * 1200 * KPAD * 2);   // (w_l @ wih)^T per layer
  u16* whhT  = (u16*)alloc((size_t)1200 * KPAD * 2);
  u16* wihT  = (u16*)alloc((size_t)1200 * KPAD * 2);
  u16* wPad  = (u16*)alloc((size_t)3 * 400 * KPAD * 2);
  u16* embB  = (u16*)alloc((size_t)embN * 2);              // single slab, reused per group
  float* pooled = (float*)alloc((size_t)128 * 1200 * 4);
  float* mAb = (float*)alloc((size_t)128 * 1000 * 4);
  float* mBb = (float*)alloc((size_t)128 * 1000 * 4);
  float* wtb = (float*)alloc((size_t)1200 * 1000 * 4);
  int* offs  = (int*)alloc((size_t)(N + 1) * 4);
  int* cur   = (int*)alloc((size_t)N * 4);
  int* srcl  = (int*)alloc((size_t)E * 4);
  int* bsum  = (int*)alloc(4096);
  int* segs  = (int*)alloc(1024);
  if (off > ws_size) return;

  const int NB = (N + 1 + 1023) / 1024;
  const int MT = (N + 127) / 128;
  const int nwg_gru = MT * 26;
  const int MT_f = (1200 + 127) / 128;       // 10
  const int nwg_f = MT_f * 7;                // 70

  hipMemsetAsync(pooled, 0, (size_t)128 * 1200 * 4, stream);

  for (int g = 0; g < 3; g++){
    const int*   x    = (const int*)  d_in[g * 9 + 0];
    const int*   ei   = (const int*)  d_in[g * 9 + 1];
    const int*   bseg = (const int*)  d_in[g * 9 + 2];
    const float* emb  = (const float*)d_in[g * 9 + 3];
    const float* w    = (const float*)d_in[g * 9 + 4];
    const float* wih  = (const float*)d_in[g * 9 + 5];
    const float* bihp = (const float*)d_in[g * 9 + 6];
    const float* whh  = (const float*)d_in[g * 9 + 7];
    const float* bhhp = (const float*)d_in[g * 9 + 8];

    hipMemsetAsync(offs, 0, (size_t)(N + 1) * 4, stream);
    count_k<<<(E + 255) / 256, 256, 0, stream>>>(ei, offs, E);
    scan_blk<<<NB, 1024, 0, stream>>>(offs, bsum, N + 1);
    scan_blk<<<1, 1024, 0, stream>>>(bsum, (int*)nullptr, NB);
    scan_add<<<(N + 1 + 255) / 256, 256, 0, stream>>>(offs, bsum, cur, N + 1, N);
    fill_k<<<(E + 255) / 256, 256, 0, stream>>>(ei, cur, srcl, E);
    bound_k<<<1, 256, 0, stream>>>(bseg, segs, N);

    // weight prep: whhT, wihT transposes; wPad cast; wcT_l = gemm(wihT, wPad_l)
    convw_k<<<(1200 * KPAD + 255) / 256, 256, 0, stream>>>(whh, whhT, 1200, 1200);
    convw_k<<<(1200 * KPAD + 255) / 256, 256, 0, stream>>>(wih, wihT, 1200, 1200);
    pad_w<<<(3 * 400 * KPAD + 255) / 256, 256, 0, stream>>>(w, wPad, 3 * 400);
    gemm_msg<<<nwg_f * 3, 256, 0, stream>>>(wihT, wPad, wcT, 1200, nwg_f, 3);

    cast_emb<<<(embN + 255) / 256, 256, 0, stream>>>(emb, embB, embN);
    embed_k<<<(N * 104 + 255) / 256, 256, 0, stream>>>(x, embB, hA, N);

    u16* hcur = hA; u16* hoth = hB;
    for (int l = 0; l < 3; l++){
      seg_sum<<<(N + 3) / 4, 256, 0, stream>>>(offs, srcl, (const u32*)hcur, (u32*)hC, N);
      gemm_gru<<<nwg_gru, 256, 0, stream>>>(hC, hcur, wcT + (size_t)l * 1200 * KPAD,
                                            whhT, bihp, bhhp, hoth, N, nwg_gru);
      u16* t = hcur; hcur = hoth; hoth = t;
    }
    pool_max<<<dim3(128, 2, 4), 256, 0, stream>>>(hcur, segs, (u32*)pooled, g * 400);
  }

  const float* wl[6] = {(const float*)d_in[27], (const float*)d_in[29], (const float*)d_in[31],
                        (const float*)d_in[33], (const float*)d_in[35], (const float*)d_in[37]};
  const float* bl[6] = {(const float*)d_in[28], (const float*)d_in[30], (const float*)d_in[32],
                        (const float*)d_in[34], (const float*)d_in[36], (const float*)d_in[38]};
  int dims[7] = {1200, 1000, 750, 500, 400, 100, 4};
  const float* cin = pooled;
  for (int li = 0; li < 6; li++){
    int K = dims[li], Nout = dims[li + 1];
    wt_k<<<(K * Nout + 255) / 256, 256, 0, stream>>>(wl[li], wtb, K, Nout);
    float* cout = (li == 5) ? (float*)d_out : (((li & 1) == 0) ? mAb : mBb);
    int waves = 32 * Nout;
    mlp_dot<<<(waves + 3) / 4, 256, 0, stream>>>(cin, wtb, bl[li], cout, K, Nout);
    cin = cout;
  }
}

// Round 12
// 3749.589 us; speedup vs baseline: 1.2241x; 1.2241x over previous
//
#include <hip/hip_runtime.h>

typedef unsigned short u16;
typedef unsigned int u32;
typedef unsigned long long u64;
typedef float f32x4 __attribute__((ext_vector_type(4)));
typedef u32 u32x4 __attribute__((ext_vector_type(4)));
typedef __bf16 bf16x8 __attribute__((ext_vector_type(8)));

#define KPAD 416   // 400 padded to 13*32
#define SWZ(r) ((((u32)(r)) & 3u) ^ ((((u32)(r)) >> 2) & 3u))

__device__ __forceinline__ float bf2f(u16 v){
  u32 x = ((u32)v) << 16; float f; __builtin_memcpy(&f, &x, 4); return f;
}
__device__ __forceinline__ u16 f2bf(float f){
  u32 x; __builtin_memcpy(&x, &f, 4);
  x += 0x7fffu + ((x >> 16) & 1u);
  return (u16)(x >> 16);
}
__device__ __forceinline__ void gll16(const u16* g, void* l){
  __builtin_amdgcn_global_load_lds(
      (const __attribute__((address_space(1))) u32*)(const void*)g,
      (__attribute__((address_space(3))) u32*)l, 16, 0, 0);
}
__device__ __forceinline__ int xcd_remap(int orig, int nwg){
  int q = nwg >> 3, r = nwg & 7;
  int xcd = orig & 7, idx = orig >> 3;
  return (xcd < r ? xcd * (q + 1) : r * (q + 1) + (xcd - r) * q) + idx;
}

// ---------------- embedding: cast table to bf16, then gather as u64 -------------
__global__ void cast_emb(const float* __restrict__ src, u16* __restrict__ dst, int n){
  int t = blockIdx.x * 256 + threadIdx.x;
  if (t < n) dst[t] = f2bf(src[t]);
}
__global__ void embed_k(const int* __restrict__ x, const u16* __restrict__ embB,
                        u16* __restrict__ H, int N){
  int tid = blockIdx.x * 256 + threadIdx.x;
  if (tid >= N * 104) return;
  int n = tid / 104, cg = tid % 104, c = cg * 4;
  u64 pack = 0;
  if (c < 400){
    int t = c / 20, d = c % 20;
    int tok = x[n * 20 + t];
    pack = *(const u64*)(embB + (size_t)tok * 20 + d);   // 4 bf16, 8B-aligned
  }
  *(u64*)(H + (size_t)n * KPAD + c) = pack;
}

// ---------------- weight transpose+pad+bf16: dst[n][k] = src[k][n] -------------
__global__ void convw_k(const float* __restrict__ src, u16* __restrict__ dst,
                        int srccols, int nout){
  int tid = blockIdx.x * 256 + threadIdx.x;
  if (tid >= nout * KPAD) return;
  int k = tid % KPAD, n = tid / KPAD;
  dst[tid] = (k < 400) ? f2bf(src[(size_t)k * srccols + n]) : (u16)0;
}

// ---------------- pad+cast w: wPad[l][k][c] = bf16(w[l][k][c]), c-pad to 416 ----
__global__ void pad_w(const float* __restrict__ src, u16* __restrict__ dst, int rows){
  int tid = blockIdx.x * 256 + threadIdx.x;
  if (tid >= rows * KPAD) return;
  int k = tid / KPAD, c = tid % KPAD;
  dst[tid] = (c < 400) ? f2bf(src[(size_t)k * 400 + c]) : (u16)0;
}

// ---------------- CSR build ----------------------------------------------------
__global__ void count_k(const int* __restrict__ ei, int* __restrict__ cnt, int E){
  int t = blockIdx.x * 256 + threadIdx.x; if (t >= E) return;
  atomicAdd(&cnt[ei[E + t] + 1], 1);
}
__global__ void scan_blk(int* __restrict__ data, int* __restrict__ bsum, int total){
  __shared__ int sm[1024];
  int gid = blockIdx.x * 1024 + threadIdx.x;
  sm[threadIdx.x] = (gid < total) ? data[gid] : 0;
  __syncthreads();
  for (int off = 1; off < 1024; off <<= 1){
    int add = (threadIdx.x >= off) ? sm[threadIdx.x - off] : 0;
    __syncthreads();
    sm[threadIdx.x] += add;
    __syncthreads();
  }
  if (gid < total) data[gid] = sm[threadIdx.x];
  if (threadIdx.x == 1023 && bsum) bsum[blockIdx.x] = sm[1023];
}
// adds block prefix AND writes cur[] copy (folds old copy_k)
__global__ void scan_add(int* __restrict__ data, const int* __restrict__ bsum,
                         int* __restrict__ cur, int total, int N){
  int gid = blockIdx.x * 256 + threadIdx.x;
  if (gid >= total) return;
  int b = gid >> 10;
  int v = data[gid];
  if (b > 0){ v += bsum[b - 1]; data[gid] = v; }
  if (gid < N) cur[gid] = v;
}
__global__ void fill_k(const int* __restrict__ ei, int* __restrict__ cur,
                       int* __restrict__ srcl, int E){
  int t = blockIdx.x * 256 + threadIdx.x; if (t >= E) return;
  int d = ei[E + t];
  int p = atomicAdd(&cur[d], 1);
  srcl[p] = ei[t];
}
__global__ void bound_k(const int* __restrict__ bseg, int* __restrict__ segs, int N){
  int t = threadIdx.x; if (t > 128) return;
  int lo = 0, hi = N;
  while (lo < hi){ int mid = (lo + hi) >> 1; if (bseg[mid] < t) lo = mid + 1; else hi = mid; }
  segs[t] = lo;
}

// ---------------- hagg[n] = sum over in-edges of h[src]; wave per node ----------
// 2-edge unroll with independent row gathers to double memory-level parallelism.
__global__ void seg_sum(const int* __restrict__ offs, const int* __restrict__ srcl,
                        const u32* __restrict__ Mv, u32* __restrict__ Agg, int N){
  int n = blockIdx.x * 4 + (threadIdx.x >> 6);
  int lane = threadIdx.x & 63;
  if (n >= N || lane >= 52) return;
  int s = offs[n], e = offs[n + 1];
  const u32* Mvl = Mv + lane * 4;
  float a[8] = {0.f,0.f,0.f,0.f,0.f,0.f,0.f,0.f};
  float b[8] = {0.f,0.f,0.f,0.f,0.f,0.f,0.f,0.f};
  int i = s;
  for (; i + 1 < e; i += 2){
    int sr0 = srcl[i], sr1 = srcl[i + 1];
    u32x4 v = *(const u32x4*)(Mvl + (size_t)sr0 * 208);
    u32x4 w = *(const u32x4*)(Mvl + (size_t)sr1 * 208);
    a[0] += bf2f((u16)(v[0] & 0xffffu)); a[1] += bf2f((u16)(v[0] >> 16));
    a[2] += bf2f((u16)(v[1] & 0xffffu)); a[3] += bf2f((u16)(v[1] >> 16));
    a[4] += bf2f((u16)(v[2] & 0xffffu)); a[5] += bf2f((u16)(v[2] >> 16));
    a[6] += bf2f((u16)(v[3] & 0xffffu)); a[7] += bf2f((u16)(v[3] >> 16));
    b[0] += bf2f((u16)(w[0] & 0xffffu)); b[1] += bf2f((u16)(w[0] >> 16));
    b[2] += bf2f((u16)(w[1] & 0xffffu)); b[3] += bf2f((u16)(w[1] >> 16));
    b[4] += bf2f((u16)(w[2] & 0xffffu)); b[5] += bf2f((u16)(w[2] >> 16));
    b[6] += bf2f((u16)(w[3] & 0xffffu)); b[7] += bf2f((u16)(w[3] >> 16));
  }
  if (i < e){
    u32x4 v = *(const u32x4*)(Mvl + (size_t)srcl[i] * 208);
    a[0] += bf2f((u16)(v[0] & 0xffffu)); a[1] += bf2f((u16)(v[0] >> 16));
    a[2] += bf2f((u16)(v[1] & 0xffffu)); a[3] += bf2f((u16)(v[1] >> 16));
    a[4] += bf2f((u16)(v[2] & 0xffffu)); a[5] += bf2f((u16)(v[2] >> 16));
    a[6] += bf2f((u16)(v[3] & 0xffffu)); a[7] += bf2f((u16)(v[3] >> 16));
  }
#pragma unroll
  for (int j = 0; j < 8; j++) a[j] += b[j];
  u32* q = Agg + (size_t)n * 208 + lane * 4;
  q[0] = (u32)f2bf(a[0]) | ((u32)f2bf(a[1]) << 16);
  q[1] = (u32)f2bf(a[2]) | ((u32)f2bf(a[3]) << 16);
  q[2] = (u32)f2bf(a[4]) | ((u32)f2bf(a[5]) << 16);
  q[3] = (u32)f2bf(a[6]) | ((u32)f2bf(a[7]) << 16);
}

// ---------------- GEMM: C[M][416] = A[M][416] @ BT[ncols][416]^T ----------------
// 128x64 tile, 2-phase dbuf; per-layer weight fold (M=1200). Batched over nfold
// (BT, C) pairs; A advances every 3 folds (degenerates to A0 for nfold<=3).
__launch_bounds__(256, 2)
__global__ void gemm_msg(const u16* __restrict__ A0, const u16* __restrict__ BT0,
                         u16* __restrict__ C0, int M, int nwg, int nfold){
  __shared__ __align__(16) u16 smem[2][192 * 32];   // per buf: lA 8192B + lB 4096B
  const int tid = threadIdx.x, lane = tid & 63, wave = tid >> 6;
  const int wgall = xcd_remap(blockIdx.x, nwg * nfold);
  const int fold = wgall / nwg, wg = wgall % nwg;
  const u16* A = A0 + (size_t)(fold / 3) * 1200 * KPAD;
  const u16* BT = BT0 + (size_t)fold * 400 * KPAD;
  u16* C = C0 + (size_t)fold * 1200 * KPAD;
  const int m0 = (wg / 7) * 128, n0 = (wg % 7) * 64;

  const u16* gsrc[3]; u32 ldo[3];
#pragma unroll
  for (int i = 0; i < 2; i++){
    u32 o = (u32)(wave * 2 + i) * 1024 + (u32)lane * 16;
    u32 r = o >> 6, cch = (o >> 4) & 3;
    int grow = m0 + (int)r; if (grow > M - 1) grow = M - 1;
    gsrc[i] = A + (size_t)grow * KPAD + ((cch ^ SWZ(r)) << 3);
    ldo[i] = o;
  }
  {
    u32 o = (u32)wave * 1024 + (u32)lane * 16;
    u32 r = o >> 6, cch = (o >> 4) & 3;
    int gn = n0 + (int)r; if (gn > 399) gn = 399;
    gsrc[2] = BT + (size_t)gn * KPAD + ((cch ^ SWZ(r)) << 3);
    ldo[2] = 8192 + o;
  }
  auto stage = [&](int p, int ks){
#pragma unroll
    for (int i = 0; i < 3; i++)
      gll16(gsrc[i] + ks * 32, (char*)smem + (size_t)p * 12288 + ldo[i]);
  };

  const int g = lane >> 4, rl = lane & 15;
  const int ar0 = wave * 32 + rl, ar1 = ar0 + 16;
  const u32 aoff0 = (u32)ar0 * 64 + ((g ^ SWZ(ar0)) << 4);
  const u32 aoff1 = (u32)ar1 * 64 + ((g ^ SWZ(ar1)) << 4);
  u32 boff[4];
#pragma unroll
  for (int j = 0; j < 4; j++){
    int br = j * 16 + rl;
    boff[j] = 8192u + (u32)br * 64 + ((g ^ SWZ(br)) << 4);
  }

  f32x4 zero = {0.f, 0.f, 0.f, 0.f};
  f32x4 acc[2][4];
#pragma unroll
  for (int i = 0; i < 2; i++)
#pragma unroll
    for (int j = 0; j < 4; j++) acc[i][j] = zero;

  stage(0, 0);
  __syncthreads();
  int cur = 0;
  for (int ks = 0; ks < 13; ks++){
    if (ks < 12) stage(cur ^ 1, ks + 1);
    const char* sb = (const char*)smem + (size_t)cur * 12288;
    bf16x8 a0 = *(const bf16x8*)(sb + aoff0);
    bf16x8 a1 = *(const bf16x8*)(sb + aoff1);
#pragma unroll
    for (int j = 0; j < 4; j++){
      bf16x8 bb = *(const bf16x8*)(sb + boff[j]);
      acc[0][j] = __builtin_amdgcn_mfma_f32_16x16x32_bf16(a0, bb, acc[0][j], 0, 0, 0);
      acc[1][j] = __builtin_amdgcn_mfma_f32_16x16x32_bf16(a1, bb, acc[1][j], 0, 0, 0);
    }
    __syncthreads();
    cur ^= 1;
  }

  const int rsub = (lane >> 4) * 4;
#pragma unroll
  for (int i = 0; i < 2; i++){
#pragma unroll
    for (int j = 0; j < 4; j++){
      int col = n0 + j * 16 + rl;
      if (col >= KPAD) continue;
#pragma unroll
      for (int r = 0; r < 4; r++){
        int row = m0 + wave * 32 + i * 16 + rsub + r;
        if (row >= M) continue;
        C[(size_t)row * KPAD + col] = (col < 400) ? f2bf(acc[i][j][r]) : (u16)0;
      }
    }
  }
}

// ---------------- fused GRU GEMM (R1/R10 structure; launch_bounds 256,3) --------
// A fragments direct global->reg (rows are wave-private).
// B triple-buffered in LDS, staged 2 k-steps ahead; counted s_waitcnt vmcnt(7)
// + raw s_barrier per step (never vmcnt(0) in the loop).
// __launch_bounds__(256,3): cap regs at ~170 to allow 3 blocks/CU (12 waves).
__launch_bounds__(256, 3)
__global__ void gemm_gru(const u16* __restrict__ AG, const u16* __restrict__ AH,
                         const u16* __restrict__ WCT, const u16* __restrict__ WHHT,
                         const float* __restrict__ bih, const float* __restrict__ bhh,
                         u16* __restrict__ Out, int M, int nwg){
  __shared__ __align__(16) u16 lB[3][6144];    // 3 bufs x 12KB: 6 tiles x 32 x 64B
  const int tid = threadIdx.x, lane = tid & 63, wave = tid >> 6;
  const int wg = xcd_remap(blockIdx.x, nwg);
  const int m0 = (wg / 13) * 128, c0 = (wg % 13) * 32;

  const u16* gsrcB[3]; u32 ldoB[3];
#pragma unroll
  for (int ii = 0; ii < 3; ii++){
    int id = wave * 3 + ii;
    int tile = id >> 1, half = id & 1;
    const u16* Wsrc = (tile < 3) ? WCT : WHHT;
    int s = (tile < 3) ? tile : tile - 3;
    u32 o = (u32)half * 1024 + (u32)lane * 16;
    u32 r = o >> 6, cch = (o >> 4) & 3;
    int ncol = c0 + (int)r; if (ncol > 399) ncol = 399;
    gsrcB[ii] = Wsrc + (size_t)(s * 400 + ncol) * KPAD + ((cch ^ SWZ(r)) << 3);
    ldoB[ii] = (u32)tile * 2048 + o;
  }
  auto stageB = [&](int p, int ks){
#pragma unroll
    for (int ii = 0; ii < 3; ii++)
      gll16(gsrcB[ii] + ks * 32, (char*)(&lB[0][0]) + (size_t)p * 12288 + ldoB[ii]);
  };

  const int g = lane >> 4, rl = lane & 15;
  int rr0 = m0 + wave * 32 + rl;      if (rr0 > M - 1) rr0 = M - 1;
  int rr1 = m0 + wave * 32 + 16 + rl; if (rr1 > M - 1) rr1 = M - 1;
  const u16* pAG0 = AG + (size_t)rr0 * KPAD + g * 8;
  const u16* pAG1 = AG + (size_t)rr1 * KPAD + g * 8;
  const u16* pAH0 = AH + (size_t)rr0 * KPAD + g * 8;
  const u16* pAH1 = AH + (size_t)rr1 * KPAD + g * 8;

  u32 boffj[2];
#pragma unroll
  for (int j = 0; j < 2; j++){
    int br = j * 16 + rl;
    boffj[j] = (u32)br * 64 + ((g ^ SWZ(br)) << 4);
  }

  f32x4 zero = {0.f, 0.f, 0.f, 0.f};
  f32x4 acc[6][2][2];
#pragma unroll
  for (int t = 0; t < 6; t++)
#pragma unroll
    for (int i = 0; i < 2; i++)
#pragma unroll
      for (int j = 0; j < 2; j++) acc[t][i][j] = zero;

  bf16x8 aX[4], aY[4];
  auto loadA = [&](bf16x8 (&d)[4], int ks){
    d[0] = *(const bf16x8*)(pAG0 + ks * 32);
    d[1] = *(const bf16x8*)(pAG1 + ks * 32);
    d[2] = *(const bf16x8*)(pAH0 + ks * 32);
    d[3] = *(const bf16x8*)(pAH1 + ks * 32);
  };

  auto body = [&](bf16x8 (&ac)[4], bf16x8 (&an)[4], int k){
    asm volatile("s_waitcnt vmcnt(7)" ::: "memory");
    __builtin_amdgcn_s_barrier();
    __builtin_amdgcn_sched_barrier(0);
    if (k + 2 <= 12) stageB((k + 2) % 3, k + 2);   // 3 gll16
    if (k + 1 <= 12) loadA(an, k + 1);             // 4 reg loads
    const char* sb = (const char*)(&lB[0][0]) + (size_t)(k % 3) * 12288;
    __builtin_amdgcn_s_setprio(1);
#pragma unroll
    for (int t = 0; t < 6; t++){
      bf16x8 b0 = *(const bf16x8*)(sb + t * 2048 + boffj[0]);
      bf16x8 b1 = *(const bf16x8*)(sb + t * 2048 + boffj[1]);
      bf16x8 x0 = (t < 3) ? ac[0] : ac[2];
      bf16x8 x1 = (t < 3) ? ac[1] : ac[3];
      acc[t][0][0] = __builtin_amdgcn_mfma_f32_16x16x32_bf16(x0, b0, acc[t][0][0], 0, 0, 0);
      acc[t][0][1] = __builtin_amdgcn_mfma_f32_16x16x32_bf16(x0, b1, acc[t][0][1], 0, 0, 0);
      acc[t][1][0] = __builtin_amdgcn_mfma_f32_16x16x32_bf16(x1, b0, acc[t][1][0], 0, 0, 0);
      acc[t][1][1] = __builtin_amdgcn_mfma_f32_16x16x32_bf16(x1, b1, acc[t][1][1], 0, 0, 0);
    }
    __builtin_amdgcn_s_setprio(0);
  };

  // prologue: pin stage(buf0) as the oldest VMEM batch, then warm the pipe.
  stageB(0, 0);
  asm volatile("" ::: "memory");
  loadA(aX, 0);
  stageB(1, 1);

  body(aX, aY, 0);  body(aY, aX, 1);  body(aX, aY, 2);  body(aY, aX, 3);
  body(aX, aY, 4);  body(aY, aX, 5);  body(aX, aY, 6);  body(aY, aX, 7);
  body(aX, aY, 8);  body(aY, aX, 9);  body(aX, aY, 10); body(aY, aX, 11);
  body(aX, aY, 12);

  const int rsub = (lane >> 4) * 4;
#pragma unroll
  for (int j = 0; j < 2; j++){
    int col = c0 + j * 16 + rl;
    bool valid = col < 400;
    float bir = 0, biz = 0, bin = 0, bhr = 0, bhz = 0, bhn = 0;
    if (valid){
      bir = bih[col]; biz = bih[400 + col]; bin = bih[800 + col];
      bhr = bhh[col]; bhz = bhh[400 + col]; bhn = bhh[800 + col];
    }
#pragma unroll
    for (int i = 0; i < 2; i++){
#pragma unroll
      for (int r = 0; r < 4; r++){
        int row = m0 + wave * 32 + i * 16 + rsub + r;
        if (row >= M) continue;
        u16 outv = 0;
        if (valid){
          float ir = acc[0][i][j][r] + bir, iz = acc[1][i][j][r] + biz, inn = acc[2][i][j][r] + bin;
          float hr = acc[3][i][j][r] + bhr, hz = acc[4][i][j][r] + bhz, hn = acc[5][i][j][r] + bhn;
          float rg = 1.f / (1.f + __expf(-(ir + hr)));
          float zg = 1.f / (1.f + __expf(-(iz + hz)));
          float nx = inn + rg * hn;
          float tn = 1.f - 2.f / (1.f + __expf(2.f * nx));
          float hp = bf2f(AH[(size_t)row * KPAD + col]);
          float hv = (1.f - zg) * tn + zg * hp;
          outv = f2bf(hv);
        }
        Out[(size_t)row * KPAD + col] = outv;
      }
    }
  }
}

// ---------------- pooled = segment_max(relu(h)); atomicMax on fp32 bits ---------
__global__ void pool_max(const u16* __restrict__ H, const int* __restrict__ segs,
                         u32* __restrict__ pooled, int goff){
  int b = blockIdx.x;
  int c = blockIdx.y * 256 + threadIdx.x;
  if (c >= 400) return;
  int s = segs[b], e = segs[b + 1], len = e - s;
  int chunk = blockIdx.z;
  int cs = s + (int)((long long)len * chunk / 4);
  int ce = s + (int)((long long)len * (chunk + 1) / 4);
  float mx = 0.f;
  for (int n = cs; n < ce; n++) mx = fmaxf(mx, bf2f(H[(size_t)n * KPAD + c]));
  if (mx > 0.f){
    u32 bits; __builtin_memcpy(&bits, &mx, 4);
    atomicMax(&pooled[b * 1200 + goff + c], bits);
  }
}

// ---------------- MLP: transpose W then wave-per-(4 rows x 1 col) dot -----------
__global__ void wt_k(const float* __restrict__ src, float* __restrict__ dst,
                     int K, int Nout){
  int t = blockIdx.x * 256 + threadIdx.x;
  if (t >= K * Nout) return;
  int n = t / K, k = t % K;
  dst[t] = src[(size_t)k * Nout + n];
}
__global__ void mlp_dot(const float* __restrict__ A, const float* __restrict__ WT,
                        const float* __restrict__ bias, float* __restrict__ out,
                        int K, int Nout){
  int gw = (int)((blockIdx.x * 256u + threadIdx.x) >> 6);
  int lane = threadIdx.x & 63;
  if (gw >= 32 * Nout) return;
  int mq = gw / Nout, n = gw % Nout;
  const float* w  = WT + (size_t)n * K;
  const float* a0 = A + (size_t)(mq * 4 + 0) * K;
  const float* a1 = A + (size_t)(mq * 4 + 1) * K;
  const float* a2 = A + (size_t)(mq * 4 + 2) * K;
  const float* a3 = A + (size_t)(mq * 4 + 3) * K;
  float c0 = 0.f, c1 = 0.f, c2 = 0.f, c3 = 0.f;
  for (int k = lane; k < K; k += 64){
    float wv = w[k];
    c0 = fmaf(a0[k], wv, c0);
    c1 = fmaf(a1[k], wv, c1);
    c2 = fmaf(a2[k], wv, c2);
    c3 = fmaf(a3[k], wv, c3);
  }
#pragma unroll
  for (int off = 32; off; off >>= 1){
    c0 += __shfl_xor(c0, off);
    c1 += __shfl_xor(c1, off);
    c2 += __shfl_xor(c2, off);
    c3 += __shfl_xor(c3, off);
  }
  if (lane == 0){
    float bn = bias[n];
    out[(size_t)(mq * 4 + 0) * Nout + n] = fmaxf(c0 + bn, 0.f);
    out[(size_t)(mq * 4 + 1) * Nout + n] = fmaxf(c1 + bn, 0.f);
    out[(size_t)(mq * 4 + 2) * Nout + n] = fmaxf(c2 + bn, 0.f);
    out[(size_t)(mq * 4 + 3) * Nout + n] = fmaxf(c3 + bn, 0.f);
  }
}

// ------------------------------------------------------------------------------
extern "C" void kernel_launch(void* const* d_in, const int* in_sizes, int n_in,
                              void* d_out, int out_size, void* d_ws, size_t ws_size,
                              hipStream_t stream){
  const int N = in_sizes[2];          // 100000
  const int E = in_sizes[1] / 2;      // 400000
  const int embN = in_sizes[3];       // V*D elements (f32)

  char* base = (char*)d_ws;
  size_t off = 0;
  auto alloc = [&](size_t sz) -> char* {
    char* r = base + off;
    off += (sz + 255) & ~(size_t)255;
    return r;
  };
  u16* hA    = (u16*)alloc((size_t)N * KPAD * 2);
  u16* hB    = (u16*)alloc((size_t)N * KPAD * 2);
  u16* hC    = (u16*)alloc((size_t)N * KPAD * 2);
  u16* wcT   = (u16*)alloc((size_t)3 * 1200 * KPAD * 2);   // (w_l @ wih)^T per layer
  u16* whhT  = (u16*)alloc((size_t)1200 * KPAD * 2);
  u16* wihT  = (u16*)alloc((size_t)1200 * KPAD * 2);
  u16* wPad  = (u16*)alloc((size_t)3 * 400 * KPAD * 2);
  u16* embB  = (u16*)alloc((size_t)embN * 2);              // single slab, reused per group
  float* pooled = (float*)alloc((size_t)128 * 1200 * 4);
  float* mAb = (float*)alloc((size_t)128 * 1000 * 4);
  float* mBb = (float*)alloc((size_t)128 * 1000 * 4);
  float* wtb = (float*)alloc((size_t)1200 * 1000 * 4);
  int* offs  = (int*)alloc((size_t)(N + 1) * 4);
  int* cur   = (int*)alloc((size_t)N * 4);
  int* srcl  = (int*)alloc((size_t)E * 4);
  int* bsum  = (int*)alloc(4096);
  int* segs  = (int*)alloc(1024);
  if (off > ws_size) return;

  const int NB = (N + 1 + 1023) / 1024;
  const int MT = (N + 127) / 128;
  const int nwg_gru = MT * 13;
  const int MT_f = (1200 + 127) / 128;       // 10
  const int nwg_f = MT_f * 7;                // 70

  hipMemsetAsync(pooled, 0, (size_t)128 * 1200 * 4, stream);

  for (int g = 0; g < 3; g++){
    const int*   x    = (const int*)  d_in[g * 9 + 0];
    const int*   ei   = (const int*)  d_in[g * 9 + 1];
    const int*   bseg = (const int*)  d_in[g * 9 + 2];
    const float* emb  = (const float*)d_in[g * 9 + 3];
    const float* w    = (const float*)d_in[g * 9 + 4];
    const float* wih  = (const float*)d_in[g * 9 + 5];
    const float* bihp = (const float*)d_in[g * 9 + 6];
    const float* whh  = (const float*)d_in[g * 9 + 7];
    const float* bhhp = (const float*)d_in[g * 9 + 8];

    hipMemsetAsync(offs, 0, (size_t)(N + 1) * 4, stream);
    count_k<<<(E + 255) / 256, 256, 0, stream>>>(ei, offs, E);
    scan_blk<<<NB, 1024, 0, stream>>>(offs, bsum, N + 1);
    scan_blk<<<1, 1024, 0, stream>>>(bsum, (int*)nullptr, NB);
    scan_add<<<(N + 1 + 255) / 256, 256, 0, stream>>>(offs, bsum, cur, N + 1, N);
    fill_k<<<(E + 255) / 256, 256, 0, stream>>>(ei, cur, srcl, E);
    bound_k<<<1, 256, 0, stream>>>(bseg, segs, N);

    // weight prep: whhT, wihT transposes; wPad cast; wcT_l = gemm(wihT, wPad_l)
    convw_k<<<(1200 * KPAD + 255) / 256, 256, 0, stream>>>(whh, whhT, 1200, 1200);
    convw_k<<<(1200 * KPAD + 255) / 256, 256, 0, stream>>>(wih, wihT, 1200, 1200);
    pad_w<<<(3 * 400 * KPAD + 255) / 256, 256, 0, stream>>>(w, wPad, 3 * 400);
    gemm_msg<<<nwg_f * 3, 256, 0, stream>>>(wihT, wPad, wcT, 1200, nwg_f, 3);

    cast_emb<<<(embN + 255) / 256, 256, 0, stream>>>(emb, embB, embN);
    embed_k<<<(N * 104 + 255) / 256, 256, 0, stream>>>(x, embB, hA, N);

    u16* hcur = hA; u16* hoth = hB;
    for (int l = 0; l < 3; l++){
      seg_sum<<<(N + 3) / 4, 256, 0, stream>>>(offs, srcl, (const u32*)hcur, (u32*)hC, N);
      gemm_gru<<<nwg_gru, 256, 0, stream>>>(hC, hcur, wcT + (size_t)l * 1200 * KPAD,
                                            whhT, bihp, bhhp, hoth, N, nwg_gru);
      u16* t = hcur; hcur = hoth; hoth = t;
    }
    pool_max<<<dim3(128, 2, 4), 256, 0, stream>>>(hcur, segs, (u32*)pooled, g * 400);
  }

  const float* wl[6] = {(const float*)d_in[27], (const float*)d_in[29], (const float*)d_in[31],
                        (const float*)d_in[33], (const float*)d_in[35], (const float*)d_in[37]};
  const float* bl[6] = {(const float*)d_in[28], (const float*)d_in[30], (const float*)d_in[32],
                        (const float*)d_in[34], (const float*)d_in[36], (const float*)d_in[38]};
  int dims[7] = {1200, 1000, 750, 500, 400, 100, 4};
  const float* cin = pooled;
  for (int li = 0; li < 6; li++){
    int K = dims[li], Nout = dims[li + 1];
    wt_k<<<(K * Nout + 255) / 256, 256, 0, stream>>>(wl[li], wtb, K, Nout);
    float* cout = (li == 5) ? (float*)d_out : (((li & 1) == 0) ? mAb : mBb);
    int waves = 32 * Nout;
    mlp_dot<<<(waves + 3) / 4, 256, 0, stream>>>(cin, wtb, bl[li], cout, K, Nout);
    cin = cout;
  }
}